// Round 15
// baseline (54.793 us; speedup 1.0000x reference)
//
#include <hip/hip_runtime.h>
#include <hip/hip_bf16.h>
#include <math.h>

// Problem constants
#define B_    16
#define C_    256
#define L_    64
#define N_    8192
#define HEAD_ 8
#define HC_   32        // C/HEAD
#define M_    12
#define BL_   1024      // B*L

#define SQRT32F 5.656854249492380f
#define PI_F    3.14159265358979323846f
#define BN_INV  0.99999500003749969f     // 1/sqrt(1+1e-5)

typedef float v4f __attribute__((ext_vector_type(4)));

// ---------------------------------------------------------------------------
// Kernel 1: qkv = enc_w (768x256) @ X (256x1024) + enc_b   (R7-proven)
// Grid (16, 25): y<24 -> 32x64 GEMM tiles (384 blocks);
//                y==24,x==0 -> qv = dec_w @ mask_token + dec_b
// ---------------------------------------------------------------------------
__global__ __launch_bounds__(128) void qkv_gemm(const float* __restrict__ enc_w,
                                                const float* __restrict__ enc_b,
                                                const float* __restrict__ xt,
                                                const float* __restrict__ dec_w,
                                                const float* __restrict__ dec_b,
                                                const float* __restrict__ mt,
                                                float* __restrict__ Y,
                                                float* __restrict__ qv_out) {
    __shared__ float As_t[32][36];   // [kk][r] transposed A, pad 36
    __shared__ float Bs[32][64];
    const int t = threadIdx.x;       // 0..127

    if (blockIdx.y == 24) {
        if (blockIdx.x != 0) return;
        __shared__ float mts[C_];
        mts[t] = mt[t];
        mts[t + 128] = mt[t + 128];
        __syncthreads();
        #pragma unroll
        for (int rr = 0; rr < 2; ++rr) {
            int r = t + rr * 128;
            const float* wrow = dec_w + (size_t)r * C_;
            float s = 0.f;
            #pragma unroll 8
            for (int c4 = 0; c4 < C_; c4 += 4) {
                float4 w4 = *reinterpret_cast<const float4*>(&wrow[c4]);
                float4 m4 = *reinterpret_cast<const float4*>(&mts[c4]);
                s += w4.x * m4.x + w4.y * m4.y + w4.z * m4.z + w4.w * m4.w;
            }
            qv_out[r] = s + dec_b[r];
        }
        return;
    }

    const int b  = blockIdx.x;           // 0..15 (col tile)
    const int o0 = blockIdx.y * 32;      // row tile
    const float* xb = xt + (size_t)b * (C_ * L_);
    const int tx = t & 15;               // cols tx*4
    const int ty = t >> 4;               // rows ty*4 (0..7)
    float4 acc[4] = {};

    for (int k0 = 0; k0 < 256; k0 += 32) {
        #pragma unroll
        for (int i = 0; i < 2; ++i) {
            int q = t + i * 128;             // 0..255 quads
            int kk4 = (q & 7) * 4, r = q >> 3;
            float4 w4 = *reinterpret_cast<const float4*>(
                &enc_w[(size_t)(o0 + r) * 256 + k0 + kk4]);
            As_t[kk4 + 0][r] = w4.x;
            As_t[kk4 + 1][r] = w4.y;
            As_t[kk4 + 2][r] = w4.z;
            As_t[kk4 + 3][r] = w4.w;
        }
        #pragma unroll
        for (int i = 0; i < 4; ++i) {
            int q = t + i * 128;             // 0..511 quads
            int jj4 = (q & 15) * 4, kk = q >> 4;
            *reinterpret_cast<float4*>(&Bs[kk][jj4]) =
                *reinterpret_cast<const float4*>(&xb[(k0 + kk) * 64 + jj4]);
        }
        __syncthreads();
        #pragma unroll
        for (int kk = 0; kk < 32; ++kk) {
            float4 a4 = *reinterpret_cast<const float4*>(&As_t[kk][ty * 4]);
            float4 b4 = *reinterpret_cast<const float4*>(&Bs[kk][tx * 4]);
            float as[4] = {a4.x, a4.y, a4.z, a4.w};
            #pragma unroll
            for (int ii = 0; ii < 4; ++ii) {
                acc[ii].x += as[ii] * b4.x; acc[ii].y += as[ii] * b4.y;
                acc[ii].z += as[ii] * b4.z; acc[ii].w += as[ii] * b4.w;
            }
        }
        __syncthreads();
    }
    #pragma unroll
    for (int ii = 0; ii < 4; ++ii) {
        int o = o0 + ty * 4 + ii;
        float bias = enc_b[o];
        float4 w = acc[ii];
        w.x += bias; w.y += bias; w.z += bias; w.w += bias;
        *reinterpret_cast<float4*>(&Y[(size_t)o * BL_ + b * 64 + tx * 4]) = w;
    }
}

// ---------------------------------------------------------------------------
// Kernel 2: attention + Fourier + residual + decoder per (b,h).
// 128 blocks x 512 threads. Phases = R14 proven forms; qkv staged from Y.
// ---------------------------------------------------------------------------
__global__ __launch_bounds__(512) void attn_dec(
    const float* __restrict__ Y, const float* __restrict__ xt,
    const float* __restrict__ weights, const float* __restrict__ qv_in,
    const float* __restrict__ mt, float* __restrict__ xnp_out)
{
    __shared__ float qkv_s[96][68];       // rows 0..31 q, 32..63 k, 64..95 v
    __shared__ float P[L_][68];
    __shared__ float enc_t[HC_][68];
    __shared__ float xts[HC_][68];        // xt h-slice for residual
    __shared__ float wts[HC_][24];
    __shared__ float qvs[HC_];
    __shared__ float aw[L_];
    const int t = threadIdx.x;            // 0..511
    const int b = blockIdx.x >> 3;
    const int h = blockIdx.x & 7;

    // ---- stage: qkv slice (1536 quads), xt h-slice (512 quads), wts, qv ----
    #pragma unroll
    for (int i = 0; i < 3; ++i) {
        int idx = t + i * 512;            // 0..1535
        int row = idx >> 4, q4 = (idx & 15) * 4;
        int o = (row >> 5) * C_ + h * HC_ + (row & 31);
        *reinterpret_cast<float4*>(&qkv_s[row][q4]) =
            *reinterpret_cast<const float4*>(&Y[(size_t)o * BL_ + b * 64 + q4]);
    }
    {
        int cc = t >> 4, q4 = (t & 15) * 4;
        *reinterpret_cast<float4*>(&xts[cc][q4]) =
            *reinterpret_cast<const float4*>(
                &xt[((size_t)b * C_ + h * HC_ + cc) * L_ + q4]);
    }
    #pragma unroll
    for (int idx = t; idx < HC_ * 24; idx += 512)
        wts[idx / 24][idx % 24] = weights[(h * HC_) * 24 + idx];
    if (t < HC_) qvs[t] = qv_in[h * HC_ + t];
    __syncthreads();

    // ---- phase 3a: scores, 2l x 4lp tile, ALL 512 threads ----
    {
        const int l0  = (t >> 4) * 2;
        const int lp0 = (t & 15) * 4;
        float sc[2][4] = {};
        #pragma unroll
        for (int cc = 0; cc < HC_; ++cc) {
            float2 q2 = *reinterpret_cast<const float2*>(&qkv_s[cc][l0]);
            float4 k4 = *reinterpret_cast<const float4*>(&qkv_s[32 + cc][lp0]);
            sc[0][0] += q2.x * k4.x; sc[0][1] += q2.x * k4.y;
            sc[0][2] += q2.x * k4.z; sc[0][3] += q2.x * k4.w;
            sc[1][0] += q2.y * k4.x; sc[1][1] += q2.y * k4.y;
            sc[1][2] += q2.y * k4.z; sc[1][3] += q2.y * k4.w;
        }
        #pragma unroll
        for (int i = 0; i < 2; ++i) {
            float4 v = make_float4(sc[i][0] * SQRT32F, sc[i][1] * SQRT32F,
                                   sc[i][2] * SQRT32F, sc[i][3] * SQRT32F);
            *reinterpret_cast<float4*>(&P[l0 + i][lp0]) = v;
        }
    }
    __syncthreads();

    // ---- phase 3b: softmax, 8 threads/row ----
    {
        int l = t >> 3, p0 = (t & 7) * 8;
        float m = -1e30f;
        #pragma unroll
        for (int j = 0; j < 8; ++j) m = fmaxf(m, P[l][p0 + j]);
        m = fmaxf(m, __shfl_xor(m, 1));
        m = fmaxf(m, __shfl_xor(m, 2));
        m = fmaxf(m, __shfl_xor(m, 4));
        float sum = 0.f;
        #pragma unroll
        for (int j = 0; j < 8; ++j) {
            float e = __expf(P[l][p0 + j] - m);
            P[l][p0 + j] = e;
            sum += e;
        }
        sum += __shfl_xor(sum, 1);
        sum += __shfl_xor(sum, 2);
        sum += __shfl_xor(sum, 4);
        float inv = 1.0f / sum;
        #pragma unroll
        for (int j = 0; j < 8; ++j) P[l][p0 + j] *= inv;
    }
    __syncthreads();

    // ---- phase 3c: PV (2l x 2cc) + Fourier recurrence + residual ----
    {
        const int l0 = (t & 31) * 2;
        const int c0 = (t >> 5) * 2;
        float a[2][2] = {};
        #pragma unroll
        for (int sq = 0; sq < 16; ++sq) {
            float4 p0v = *reinterpret_cast<const float4*>(&P[l0 + 0][sq * 4]);
            float4 p1v = *reinterpret_cast<const float4*>(&P[l0 + 1][sq * 4]);
            float4 v0v = *reinterpret_cast<const float4*>(&qkv_s[64 + c0 + 0][sq * 4]);
            float4 v1v = *reinterpret_cast<const float4*>(&qkv_s[64 + c0 + 1][sq * 4]);
            a[0][0] += p0v.x * v0v.x + p0v.y * v0v.y + p0v.z * v0v.z + p0v.w * v0v.w;
            a[0][1] += p0v.x * v1v.x + p0v.y * v1v.y + p0v.z * v1v.z + p0v.w * v1v.w;
            a[1][0] += p1v.x * v0v.x + p1v.y * v0v.y + p1v.z * v0v.z + p1v.w * v0v.w;
            a[1][1] += p1v.x * v1v.x + p1v.y * v1v.y + p1v.z * v1v.z + p1v.w * v1v.w;
        }
        #pragma unroll
        for (int j = 0; j < 2; ++j) {
            int cc = c0 + j;
            const float* wrf = wts[cc];
            float vv[2];
            #pragma unroll
            for (int i = 0; i < 2; ++i) {
                float val = xts[cc][l0 + i] + wrf[M_];   // m=0: sin=0, cos=1
                float base = a[i][j] * (PI_F / (float)M_);
                float s1, c1;
                __sincosf(base, &s1, &c1);
                float sm = 0.f, cm = 1.f;
                #pragma unroll
                for (int m = 1; m < M_; ++m) {
                    float sp = sm * c1 + cm * s1;
                    float cp = cm * c1 - sm * s1;
                    sm = sp; cm = cp;
                    val += wrf[m] * sm + wrf[M_ + m] * cm;
                }
                vv[i] = val;
            }
            *reinterpret_cast<float2*>(&enc_t[cc][l0]) =
                make_float2(vv[0], vv[1]);
        }
    }
    __syncthreads();

    // ---- phase 4: decoder attention (constant query) ----
    if (t < L_) {
        float s = 0.f;
        #pragma unroll
        for (int cc = 0; cc < HC_; ++cc) s += qvs[cc] * enc_t[cc][t];
        s *= SQRT32F;
        float m = s;
        #pragma unroll
        for (int off = 32; off >= 1; off >>= 1) m = fmaxf(m, __shfl_xor(m, off));
        float e = __expf(s - m);
        float sum = e;
        #pragma unroll
        for (int off = 32; off >= 1; off >>= 1) sum += __shfl_xor(sum, off);
        aw[t] = e / sum;
    }
    __syncthreads();
    if (t < HC_) {
        float a = 0.f;
        #pragma unroll
        for (int k4 = 0; k4 < L_; k4 += 4) {
            float4 a4 = *reinterpret_cast<const float4*>(&aw[k4]);
            float4 v4 = *reinterpret_cast<const float4*>(&enc_t[t][k4]);
            a += a4.x * v4.x + a4.y * v4.y + a4.z * v4.z + a4.w * v4.w;
        }
        int c = h * HC_ + t;
        xnp_out[b * C_ + c] = a + mt[c];
    }
}

// ---------------------------------------------------------------------------
// Kernel 3: fc blocks first, nontemporal streaming stores. (proven R10)
// ---------------------------------------------------------------------------
__global__ __launch_bounds__(256) void bcast_fc(const float* __restrict__ xnp,
                                                const float* __restrict__ fc1_w,
                                                const float* __restrict__ fc1_g,
                                                const float* __restrict__ fc1_b,
                                                const float* __restrict__ fc2_w,
                                                const float* __restrict__ fc2_g,
                                                const float* __restrict__ fc2_b,
                                                float* __restrict__ out) {
    const int t = threadIdx.x;
    const int blk = blockIdx.x;
    if (blk >= 16) {
        int rowid = blk - 16;                 // (b,c) row
        float v = xnp[rowid];
        v4f V = {v, v, v, v};
        v4f* row = reinterpret_cast<v4f*>(out + (size_t)rowid * N_);
        #pragma unroll
        for (int i = 0; i < 8; ++i)
            __builtin_nontemporal_store(V, &row[t + i * 256]);   // 2048 x 16B
    } else {
        int b = blk;
        __shared__ float xs[C_];
        __shared__ float y1[C_];
        __shared__ float y2s[4];
        xs[t] = xnp[b * C_ + t];
        __syncthreads();
        {
            const float* wrow = fc1_w + (size_t)t * C_;
            float s = 0.f;
            #pragma unroll 8
            for (int c4 = 0; c4 < C_; c4 += 4) {
                float4 w4 = *reinterpret_cast<const float4*>(&wrow[c4]);
                float4 x4 = *reinterpret_cast<const float4*>(&xs[c4]);
                s += w4.x * x4.x + w4.y * x4.y + w4.z * x4.z + w4.w * x4.w;
            }
            float y = fc1_g[t] * s * BN_INV + fc1_b[t];
            y1[t] = (y >= 0.f) ? y : 0.2f * y;
        }
        __syncthreads();
        if (t < 3) {
            const float* wrow = fc2_w + t * C_;
            float s = 0.f;
            #pragma unroll 8
            for (int c4 = 0; c4 < C_; c4 += 4) {
                float4 w4 = *reinterpret_cast<const float4*>(&wrow[c4]);
                float4 x4 = *reinterpret_cast<const float4*>(&y1[c4]);
                s += w4.x * x4.x + w4.y * x4.y + w4.z * x4.z + w4.w * x4.w;
            }
            float y = fc2_g[t] * s * BN_INV + fc2_b[t];
            y2s[t] = (y >= 0.f) ? y : 0.2f * y;
        }
        __syncthreads();
        float v0 = y2s[0], v1 = y2s[1], v2 = y2s[2];
        v4f pat0 = {v0, v1, v2, v0};
        v4f pat1 = {v1, v2, v0, v1};
        v4f pat2 = {v2, v0, v1, v2};
        int r = t % 3;
        v4f a = (r == 0) ? pat0 : (r == 1) ? pat1 : pat2;
        v4f bb = (r == 0) ? pat1 : (r == 1) ? pat2 : pat0;
        v4f c = (r == 0) ? pat2 : (r == 1) ? pat0 : pat1;
        v4f* o1 = reinterpret_cast<v4f*>(
            out + (size_t)B_ * C_ * N_ + (size_t)b * (N_ * 3));
        #pragma unroll
        for (int i = 0; i < 24; i += 3) {    // 6144 float4 = 8192*3 f32
            __builtin_nontemporal_store(a,  &o1[t + (i + 0) * 256]);
            __builtin_nontemporal_store(bb, &o1[t + (i + 1) * 256]);
            __builtin_nontemporal_store(c,  &o1[t + (i + 2) * 256]);
        }
    }
}

// ---------------------------------------------------------------------------
extern "C" void kernel_launch(void* const* d_in, const int* in_sizes, int n_in,
                              void* d_out, int out_size, void* d_ws, size_t ws_size,
                              hipStream_t stream) {
    const float* xt      = (const float*)d_in[0];
    // d_in[1] = xn : unused (length N is compile-time)
    const float* weights = (const float*)d_in[2];
    const float* mt      = (const float*)d_in[3];
    const float* enc_w   = (const float*)d_in[4];
    const float* enc_b   = (const float*)d_in[5];
    const float* dec_w   = (const float*)d_in[6];
    const float* dec_b   = (const float*)d_in[7];
    const float* fc1_w   = (const float*)d_in[8];
    const float* fc1_g   = (const float*)d_in[9];
    const float* fc1_b   = (const float*)d_in[10];
    const float* fc2_w   = (const float*)d_in[11];
    const float* fc2_g   = (const float*)d_in[12];
    const float* fc2_b   = (const float*)d_in[13];

    float* ws  = (float*)d_ws;
    float* Y   = ws;                  // 786432 floats (3 MB)
    float* qv  = ws + 786432;         // 256 floats
    float* xnp = ws + 786688;         // 4096 floats

    float* out = (float*)d_out;

    qkv_gemm<<<dim3(16, 25), 128, 0, stream>>>(enc_w, enc_b, xt,
                                               dec_w, dec_b, mt, Y, qv);
    attn_dec<<<128, 512, 0, stream>>>(Y, xt, weights, qv, mt, xnp);
    bcast_fc<<<4112, 256, 0, stream>>>(xnp, fc1_w, fc1_g, fc1_b,
                                       fc2_w, fc2_g, fc2_b, out);
}